// Round 5
// baseline (62.541 us; speedup 1.0000x reference)
//
#include <hip/hip_runtime.h>

#define NREG   20
#define EDIM   768
#define DVOL   64
#define HVOL   512
#define WVOL   512
#define HW_    (HVOL * WVOL)
#define DHW_   (DVOL * HVOL * WVOL)
#define NPATCH 16384
#define BTOT   2
#define PROTO_N (NREG * EDIM)            // 15360
#define RF_N    (BTOT * PROTO_N)         // 30720 floats (output 0)
#define TOTAL_PATCHES (BTOT * NPATCH)    // 32768
#define PPW     4                        // patches per wave

// 16-byte load with only 4-byte alignment guarantee.
struct __attribute__((packed, aligned(4))) int4p { int x, y, z, w; };

// ---------------------------------------------------------------------------
// One wave per 4 consecutive patches. Lane = (yy = lane>>2) x (xl4 = lane&3).
// All 16 gathers (4 patches x 4 z-slices) issue back-to-back before any
// consumption -> 16 outstanding dwordx4 loads per wave. Reduction is fully
// in-register (packed 8-bit butterfly + unpack), no LDS, no __syncthreads.
// Blocks 0..119 also copy the prototype broadcast (output 0).
// ---------------------------------------------------------------------------
__global__ __launch_bounds__(256) void assign_kernel(
    const int*   __restrict__ seg,
    const float* __restrict__ coords,
    const float* __restrict__ proto,
    float*       __restrict__ out)
{
    // fused output 0: region_features = broadcast prototypes (120 blocks)
    if (blockIdx.x < RF_N / 256) {
        const int i = blockIdx.x * 256 + threadIdx.x;
        out[i] = proto[i >= PROTO_N ? i - PROTO_N : i];
    }

    const int lane = threadIdx.x & 63;
    const int gw   = blockIdx.x * 4 + (threadIdx.x >> 6);   // global wave id
    const int p0   = gw * PPW;                              // first patch
    const int segbase = (p0 >> 14) * DHW_;                  // b uniform per wave

    const int xl4 = lane & 3;                 // which 4-int chunk of the row
    const int yy  = lane >> 2;                // y offset 0..15

    // coords for 4 consecutive patches: 12 contiguous floats (16B-aligned)
    float c[12];
    {
        const float4* cp = (const float4*)(coords + p0 * 3);
        const float4 a = cp[0], bq = cp[1], d = cp[2];
        c[0]=a.x; c[1]=a.y; c[2]=a.z; c[3]=a.w;
        c[4]=bq.x; c[5]=bq.y; c[6]=bq.z; c[7]=bq.w;
        c[8]=d.x; c[9]=d.y; c[10]=d.z; c[11]=d.w;
    }

    int4p    q[PPW][4];          // gathered data (loads issued in prep loop)
    unsigned vm[PPW][4];         // y+x validity masks
    unsigned zbits[PPW];         // bit z set iff sz+z < ez
    float    denomv[PPW];        // max(numel,1)

#pragma unroll
    for (int p = 0; p < PPW; ++p) {
        const float c0 = c[3*p + 0] * 64.0f;    // z
        const float c1 = c[3*p + 1] * 512.0f;   // y
        const float c2 = c[3*p + 2] * 512.0f;   // x

        const int sz = (int)fmaxf(0.0f,   floorf(c0 - 2.0f));
        const int ez = (int)fminf(64.0f,  floorf(c0 + 2.0f));
        const int sy = (int)fmaxf(0.0f,   floorf(c1 - 8.0f));
        const int ey = (int)fminf(512.0f, floorf(c1 + 8.0f));
        const int sx = (int)fmaxf(0.0f,   floorf(c2 - 8.0f));
        const int ex = (int)fminf(512.0f, floorf(c2 + 8.0f));

        const int p_lo = sx + 4 * xl4;
        const int st   = min(p_lo, WVOL - 4);
        const int yi   = sy + yy;
        const unsigned vy = (yi < ey) ? 0xFFFFFFFFu : 0u;
        const int yiC  = min(yi, HVOL - 1);
        const int rowbase = segbase + yiC * WVOL + st;

#pragma unroll
        for (int j = 0; j < 4; ++j) {
            const int pos = st + j;
            vm[p][j] = (pos >= p_lo && pos < ex) ? vy : 0u;
        }
        unsigned zb = 0u;
#pragma unroll
        for (int z = 0; z < 4; ++z) {
            zb |= (sz + z < ez) ? (1u << z) : 0u;
            const int ziC = min(sz + z, DVOL - 1);
            q[p][z] = *(const int4p*)(seg + rowbase + ziC * HW_);
        }
        zbits[p] = zb;

        const float nz = (float)max(ez - sz, 0);
        const float ny = (float)max(ey - sy, 0);
        const float nx = (float)max(ex - sx, 0);
        denomv[p] = fmaxf(nz * ny * nx, 1.0f);
    }

    // ---- consume patch by patch (vmcnt waits are partial: later patches'
    // loads remain outstanding while earlier ones reduce) -------------------
#pragma unroll
    for (int p = 0; p < PPW; ++p) {
        unsigned cc[5] = {0u, 0u, 0u, 0u, 0u};

#pragma unroll
        for (int z = 0; z < 4; ++z) {
            const unsigned zm = 0u - ((zbits[p] >> z) & 1u);
            const int vals[4] = {q[p][z].x, q[p][z].y, q[p][z].z, q[p][z].w};
#pragma unroll
            for (int j = 0; j < 4; ++j) {
                const int v = vals[j] & (int)(vm[p][j] & zm);  // invalid -> 0
                const int t = v - 1;                           // -1 if none
                const unsigned inc = 1u << ((t & 3) << 3);
                const int qk = t >> 2;                         // -1: no match
#pragma unroll
                for (int k = 0; k < 5; ++k)
                    cc[k] += (qk == k) ? inc : 0u;
            }
        }

        // 3-step packed butterfly within 8-lane groups (max 128/field)
#pragma unroll
        for (int off = 1; off < 8; off <<= 1) {
#pragma unroll
            for (int k = 0; k < 5; ++k)
                cc[k] += (unsigned)__shfl_xor((int)cc[k], off);
        }

        // unpack 8-bit -> 2x16-bit, 3 more steps across the 8 groups
        unsigned lo[5], hi[5];
#pragma unroll
        for (int k = 0; k < 5; ++k) {
            lo[k] = cc[k] & 0x00FF00FFu;          // m=4k (lo16), m=4k+2 (hi16)
            hi[k] = (cc[k] >> 8) & 0x00FF00FFu;   // m=4k+1,      m=4k+3
        }
#pragma unroll
        for (int off = 8; off < 64; off <<= 1) {
#pragma unroll
            for (int k = 0; k < 5; ++k) {
                lo[k] += (unsigned)__shfl_xor((int)lo[k], off);
                hi[k] += (unsigned)__shfl_xor((int)hi[k], off);
            }
        }

        // total: packed 16-bit pairwise sums (max 2048/field), then fold
        unsigned S = 0u;
#pragma unroll
        for (int k = 0; k < 5; ++k) S += lo[k] + hi[k];
        const unsigned tot = (S & 0xFFFFu) + (S >> 16);

        // per-lane region count (lanes 0..19), static select chain
        const int r = lane & 3;
        const unsigned sLo = (lane < 4) ? lo[0] : (lane < 8) ? lo[1]
                           : (lane < 12) ? lo[2] : (lane < 16) ? lo[3] : lo[4];
        const unsigned sHi = (lane < 4) ? hi[0] : (lane < 8) ? hi[1]
                           : (lane < 12) ? hi[2] : (lane < 16) ? hi[3] : hi[4];
        const unsigned fld = (r & 1) ? sHi : sLo;
        const unsigned cnt = (r & 2) ? (fld >> 16) : (fld & 0xFFFFu);

        if (lane < NREG) {
            const float denom = denomv[p];
            const float s = (float)tot / denom + (float)NREG * 1e-6f;
            const float a = (float)cnt / denom + 1e-6f;
            out[RF_N + (p0 + p) * NREG + lane] = a / s;
        }
    }
}

// ---------------------------------------------------------------------------
extern "C" void kernel_launch(void* const* d_in, const int* in_sizes, int n_in,
                              void* d_out, int out_size, void* d_ws, size_t ws_size,
                              hipStream_t stream)
{
    const int*   seg    = (const int*)d_in[0];
    const float* coords = (const float*)d_in[1];
    const float* proto  = (const float*)d_in[2];
    float*       out    = (float*)d_out;

    hipLaunchKernelGGL(assign_kernel, dim3(TOTAL_PATCHES / (PPW * 4)), dim3(256),
                       0, stream, seg, coords, proto, out);
}

// Round 6
// 55.482 us; speedup vs baseline: 1.1272x; 1.1272x over previous
//
#include <hip/hip_runtime.h>

#define NREG   20
#define EDIM   768
#define DVOL   64
#define HVOL   512
#define WVOL   512
#define HW_    (HVOL * WVOL)
#define DHW_   (DVOL * HVOL * WVOL)
#define NPATCH 16384
#define BTOT   2
#define PROTO_N (NREG * EDIM)            // 15360
#define RF_N    (BTOT * PROTO_N)         // 30720 floats (output 0)
#define TOTAL_PATCHES (BTOT * NPATCH)    // 32768
#define NBUCKET 1024                     // 2 b x 32 zbins x 16 ybins

// workspace layout (u32 words)
#define WS_COUNTS  0
#define WS_OFFSETS 1024
#define WS_KEYS    2048
#define WS_PID     (2048 + TOTAL_PATCHES)
#define WS_C0      (WS_PID + TOTAL_PATCHES)
#define WS_C1      (WS_C0  + TOTAL_PATCHES)
#define WS_C2      (WS_C1  + TOTAL_PATCHES)

// 16-byte load with only 4-byte alignment guarantee.
struct __attribute__((packed, aligned(4))) int4p { int x, y, z, w; };

// ---------------------------------------------------------------------------
__global__ __launch_bounds__(1024) void zero_counts_kernel(unsigned* __restrict__ ws)
{
    ws[WS_COUNTS + threadIdx.x] = 0u;
}

__global__ __launch_bounds__(256) void count_kernel(
    const float* __restrict__ coords, unsigned* __restrict__ ws)
{
    const int p = blockIdx.x * 256 + threadIdx.x;
    const int b = p >> 14;
    const float zf = coords[p * 3 + 0] * 64.0f;
    const float yf = coords[p * 3 + 1] * 512.0f;
    const int zbin = min(31, ((int)zf) >> 1);     // z/2  -> 32 bins
    const int ybin = min(15, ((int)yf) >> 5);     // y/32 -> 16 bins
    const unsigned key = (unsigned)(b * 512 + zbin * 16 + ybin);
    ws[WS_KEYS + p] = key;
    atomicAdd(&ws[WS_COUNTS + key], 1u);
}

__global__ __launch_bounds__(1024) void scan_kernel(unsigned* __restrict__ ws)
{
    __shared__ unsigned tmp[NBUCKET];
    const int t = threadIdx.x;
    const unsigned v = ws[WS_COUNTS + t];
    tmp[t] = v;
    __syncthreads();
#pragma unroll
    for (int off = 1; off < NBUCKET; off <<= 1) {
        const unsigned y = (t >= off) ? tmp[t - off] : 0u;
        __syncthreads();
        tmp[t] += y;
        __syncthreads();
    }
    ws[WS_OFFSETS + t] = tmp[t] - v;              // exclusive prefix
}

__global__ __launch_bounds__(256) void scatter_kernel(
    const float* __restrict__ coords, unsigned* __restrict__ ws)
{
    const int p = blockIdx.x * 256 + threadIdx.x;
    const unsigned key  = ws[WS_KEYS + p];
    const unsigned rank = atomicAdd(&ws[WS_OFFSETS + key], 1u);
    ws[WS_PID + rank] = (unsigned)p;
    ((float*)ws)[WS_C0 + rank] = coords[p * 3 + 0];
    ((float*)ws)[WS_C1 + rank] = coords[p * 3 + 1];
    ((float*)ws)[WS_C2 + rank] = coords[p * 3 + 2];
}

// ---------------------------------------------------------------------------
// One wave per sorted slot. Patch id + coords come from ws (wave-uniform
// broadcast loads). Body identical to the R4 kernel: 4 unconditional int4
// gathers, packed 8-bit histogram, in-register butterfly finish.
// Blocks 0..119 also copy the prototype broadcast (output 0).
// ---------------------------------------------------------------------------
__global__ __launch_bounds__(256) void assign_kernel(
    const int*   __restrict__ seg,
    const unsigned* __restrict__ ws,
    const float* __restrict__ proto,
    float*       __restrict__ out)
{
    // fused output 0: region_features = broadcast prototypes (120 blocks)
    if (blockIdx.x < RF_N / 256) {
        const int i = blockIdx.x * 256 + threadIdx.x;
        out[i] = proto[i >= PROTO_N ? i - PROTO_N : i];
    }

    // XCD-chunked swizzle: 8192 blocks, 8 XCDs -> contiguous sorted ranges
    const int bid  = (int)blockIdx.x;
    const int sbid = (bid & 7) * 1024 + (bid >> 3);

    const int lane = threadIdx.x & 63;
    const int wave = threadIdx.x >> 6;
    const int slot = sbid * 4 + wave;

    const int   patch = (int)ws[WS_PID + slot];        // wave-uniform
    const float c0 = ((const float*)ws)[WS_C0 + slot] * 64.0f;   // z
    const float c1 = ((const float*)ws)[WS_C1 + slot] * 512.0f;  // y
    const float c2 = ((const float*)ws)[WS_C2 + slot] * 512.0f;  // x
    const int b = patch >> 14;

    const int sz = (int)fmaxf(0.0f,   floorf(c0 - 2.0f));
    const int ez = (int)fminf(64.0f,  floorf(c0 + 2.0f));
    const int sy = (int)fmaxf(0.0f,   floorf(c1 - 8.0f));
    const int ey = (int)fminf(512.0f, floorf(c1 + 8.0f));
    const int sx = (int)fmaxf(0.0f,   floorf(c2 - 8.0f));
    const int ex = (int)fminf(512.0f, floorf(c2 + 8.0f));

    const int xl4  = lane & 3;
    const int yy   = lane >> 2;
    const int p_lo = sx + 4 * xl4;
    const int st   = min(p_lo, WVOL - 4);
    const int yi   = sy + yy;
    const unsigned vy = (yi < ey) ? 0xFFFFFFFFu : 0u;
    const int yiC  = min(yi, HVOL - 1);
    const int rowbase = b * DHW_ + yiC * WVOL + st;

    unsigned vm[4];
#pragma unroll
    for (int j = 0; j < 4; ++j) {
        const int pos = st + j;
        vm[j] = (pos >= p_lo && pos < ex) ? vy : 0u;
    }

    // --- 4 unconditional gathers, issued back-to-back ----------------------
    int4p q0, q1, q2, q3;
    {
        const int z0 = min(sz + 0, DVOL - 1) * HW_;
        const int z1 = min(sz + 1, DVOL - 1) * HW_;
        const int z2 = min(sz + 2, DVOL - 1) * HW_;
        const int z3 = min(sz + 3, DVOL - 1) * HW_;
        q0 = *(const int4p*)(seg + rowbase + z0);
        q1 = *(const int4p*)(seg + rowbase + z1);
        q2 = *(const int4p*)(seg + rowbase + z2);
        q3 = *(const int4p*)(seg + rowbase + z3);
    }

    unsigned cc[5] = {0u, 0u, 0u, 0u, 0u};
#pragma unroll
    for (int z = 0; z < 4; ++z) {
        const unsigned zm = (sz + z < ez) ? 0xFFFFFFFFu : 0u;
        const int4p qz = (z == 0) ? q0 : (z == 1) ? q1 : (z == 2) ? q2 : q3;
        const int vals[4] = {qz.x, qz.y, qz.z, qz.w};
#pragma unroll
        for (int j = 0; j < 4; ++j) {
            const int v = vals[j] & (int)(vm[j] & zm);   // invalid -> 0
            const int t = v - 1;
            const unsigned inc = 1u << ((t & 3) << 3);
            const int qk = t >> 2;
#pragma unroll
            for (int k = 0; k < 5; ++k)
                cc[k] += (qk == k) ? inc : 0u;
        }
    }

    // 3-step packed butterfly within 8-lane groups (max 128/field)
#pragma unroll
    for (int off = 1; off < 8; off <<= 1) {
#pragma unroll
        for (int k = 0; k < 5; ++k)
            cc[k] += (unsigned)__shfl_xor((int)cc[k], off);
    }

    // unpack 8-bit -> 2x16-bit, 3 more steps across the 8 groups
    unsigned lo[5], hi[5];
#pragma unroll
    for (int k = 0; k < 5; ++k) {
        lo[k] = cc[k] & 0x00FF00FFu;
        hi[k] = (cc[k] >> 8) & 0x00FF00FFu;
    }
#pragma unroll
    for (int off = 8; off < 64; off <<= 1) {
#pragma unroll
        for (int k = 0; k < 5; ++k) {
            lo[k] += (unsigned)__shfl_xor((int)lo[k], off);
            hi[k] += (unsigned)__shfl_xor((int)hi[k], off);
        }
    }

    unsigned S = 0u;
#pragma unroll
    for (int k = 0; k < 5; ++k) S += lo[k] + hi[k];
    const unsigned tot = (S & 0xFFFFu) + (S >> 16);

    const int r = lane & 3;
    const unsigned sLo = (lane < 4) ? lo[0] : (lane < 8) ? lo[1]
                       : (lane < 12) ? lo[2] : (lane < 16) ? lo[3] : lo[4];
    const unsigned sHi = (lane < 4) ? hi[0] : (lane < 8) ? hi[1]
                       : (lane < 12) ? hi[2] : (lane < 16) ? hi[3] : hi[4];
    const unsigned fld = (r & 1) ? sHi : sLo;
    const unsigned cnt = (r & 2) ? (fld >> 16) : (fld & 0xFFFFu);

    if (lane < NREG) {
        const float nz = (float)max(ez - sz, 0);
        const float ny = (float)max(ey - sy, 0);
        const float nx = (float)max(ex - sx, 0);
        const float denom = fmaxf(nz * ny * nx, 1.0f);
        const float s = (float)tot / denom + (float)NREG * 1e-6f;
        const float a = (float)cnt / denom + 1e-6f;
        out[RF_N + patch * NREG + lane] = a / s;
    }
}

// ---------------------------------------------------------------------------
extern "C" void kernel_launch(void* const* d_in, const int* in_sizes, int n_in,
                              void* d_out, int out_size, void* d_ws, size_t ws_size,
                              hipStream_t stream)
{
    const int*   seg    = (const int*)d_in[0];
    const float* coords = (const float*)d_in[1];
    const float* proto  = (const float*)d_in[2];
    float*       out    = (float*)d_out;
    unsigned*    ws     = (unsigned*)d_ws;

    hipLaunchKernelGGL(zero_counts_kernel, dim3(1), dim3(NBUCKET), 0, stream, ws);
    hipLaunchKernelGGL(count_kernel, dim3(TOTAL_PATCHES / 256), dim3(256), 0, stream,
                       coords, ws);
    hipLaunchKernelGGL(scan_kernel, dim3(1), dim3(NBUCKET), 0, stream, ws);
    hipLaunchKernelGGL(scatter_kernel, dim3(TOTAL_PATCHES / 256), dim3(256), 0, stream,
                       coords, ws);
    hipLaunchKernelGGL(assign_kernel, dim3(TOTAL_PATCHES / 4), dim3(256), 0, stream,
                       seg, ws, proto, out);
}